// Round 2
// baseline (203.196 us; speedup 1.0000x reference)
//
#include <hip/hip_runtime.h>
#include <stdint.h>

#define S 64
#define NSQ 32
#define Lc 2048
#define Cc 512
#define Ec 128
#define OUT_H (S*NSQ*Lc)   /* 4194304 */

typedef __bf16 bf16x8 __attribute__((ext_vector_type(8)));
typedef float floatx4 __attribute__((ext_vector_type(4)));

__device__ __forceinline__ unsigned short f2bf(float f){
  union { float f; uint32_t u; } v; v.f = f;
  uint32_t r = v.u + 0x7fffu + ((v.u >> 16) & 1u);
  return (unsigned short)(r >> 16);
}

// packed f32x2 -> bf16x2 (RNE), 1 instruction on gfx950
__device__ __forceinline__ uint32_t cvt_pk_bf16(float lo, float hi){
  uint32_t r;
  asm("v_cvt_pk_bf16_f32 %0, %1, %2" : "=v"(r) : "v"(lo), "v"(hi));
  return r;
}

// XOR-swizzled LDS offset (shorts) for the x/x2 tile (row stride 512).
__device__ __forceinline__ int xoff(int row, int cg) {
  return row*512 + (((cg) ^ (row & 7)) << 3);
}

// ---------------------------------------------------------------------------
// k_prep: adapt dots (coalesced + shfl reduce); W1/W2 -> MFMA-fragment-packed
// bf16; zero logdet.   grid 512 x 256
// dynW is written TRANSPOSED for conflict-free LDS reads in k_fused:
//   thread cg (= ch>>3) reads float4 j4 at dynW[s*1536 + j4*256 + cg*4 + (0..3)]
//   element j (0..23) of thread cg = weight (ch = cg*8 + j/3, k = j%3).
// W1p: frag = ch*32 + o16; elem(lane,j) = W1[o16*16+(lane&15)][ch*32+(lane>>4)*8+j]
// W2p: frag = (k*2+jh)*16 + cc; elem(lane,j) = W2[jh*16+(lane&15)][cc*32+(lane>>4)*8+j][k]
// ---------------------------------------------------------------------------
__global__ void k_prep(const float* __restrict__ emb,
                       const float* __restrict__ Wa, const float* __restrict__ ba,
                       const float* __restrict__ Wb, const float* __restrict__ bb,
                       const float* __restrict__ W1, const float* __restrict__ W2,
                       float* __restrict__ dynW, float* __restrict__ dynB,
                       unsigned short* __restrict__ W1p, unsigned short* __restrict__ W2p,
                       float* __restrict__ out)
{
  __shared__ float embl[Ec];
  int tid = threadIdx.x;
  int b = blockIdx.x;          // 512 blocks, 8 per sample
  int s = b >> 3, g = b & 7;
  if (tid < Ec) embl[tid] = emb[s*Ec + tid];
  __syncthreads();
  {
    int w = tid >> 6, lane = tid & 63, le = lane & 31, rh = lane >> 5;
    float4 ev = *(const float4*)&embl[le*4];
    int base_o = g*256 + w*64;
    #pragma unroll 4
    for (int p = 0; p < 32; p++) {
      int ro = base_o + p*2 + rh;
      bool isA = ro < 1536;
      const float* rp = isA ? (Wa + ro*Ec) : (Wb + (ro - 1536)*Ec);
      float4 wv = *(const float4*)&rp[le*4];
      float part = wv.x*ev.x + wv.y*ev.y + wv.z*ev.z + wv.w*ev.w;
      part += __shfl_xor(part, 1, 32);
      part += __shfl_xor(part, 2, 32);
      part += __shfl_xor(part, 4, 32);
      part += __shfl_xor(part, 8, 32);
      part += __shfl_xor(part, 16, 32);
      if (le == 0) {
        if (isA) {
          // transposed write (see header comment)
          int ch = ro / 3, k = ro - ch*3;
          int cgc = ch >> 3, j = (ch & 7)*3 + k;
          dynW[s*1536 + (j >> 2)*256 + cgc*4 + (j & 3)] = part + ba[ro];
        } else {
          dynB[s*Cc + (ro - 1536)] = part + bb[ro - 1536];
        }
      }
    }
  }

  int gtid = b*256 + tid;      // 0..131071
  // W1 pack: 262144 elems, 2 per thread (j pairs)
  {
    int d0 = gtid*2;
    int j0 = d0 & 7;
    int lane = (d0 >> 3) & 63;
    int frag = d0 >> 9;
    int o16 = frag & 31, ch = frag >> 5;
    int oo = o16*16 + (lane & 15);
    int cc = ch*32 + (lane >> 4)*8 + j0;
    float2 wv = *(const float2*)&W1[oo*512 + cc];
    ((uint32_t*)W1p)[gtid] = cvt_pk_bf16(wv.x, wv.y);
  }
  // W2 pack: 49152 elems
  if (gtid < 49152) {
    int d = gtid;
    int j = d & 7;
    int lane = (d >> 3) & 63;
    int frag = d >> 9;
    int k = frag >> 5, jh = (frag >> 4) & 1, cc = frag & 15;
    int jj = jh*16 + (lane & 15);
    int c = cc*32 + (lane >> 4)*8 + j;
    W2p[d] = f2bf(W2[jj*1536 + c*3 + k]);
  }
  if (gtid < S) out[OUT_H + gtid] = 0.f;   // logdet accumulators
}

// ---------------------------------------------------------------------------
// k_fused11: vs k_fused10 —
//  - dws read conflict-free via transposed [6][64]-float4 layout (was 16-way)
//  - dbs dropped from LDS; bias read from L2-resident dynB (coalesced, before
//    barrier)
//  - s_setprio(1) around MFMA clusters (phase A + phase B conv)
//  - phase C h2 global loads issued before the B->C barrier (latency hidden)
//  - LDS compacted: 76064 B
// x2 col ll <-> global l = t*62 - 1 + ll; valid outputs ll in [1,62].
// ---------------------------------------------------------------------------
__global__ void __launch_bounds__(512, 4) k_fused11(
    const float* __restrict__ h,
    const unsigned short* __restrict__ W1p, const float* __restrict__ b1,
    const unsigned short* __restrict__ W2p, const float* __restrict__ b2,
    const float* __restrict__ dynW, const float* __restrict__ dynB,
    float* __restrict__ out)
{
  extern __shared__ char smem[];
  float* hs  = (float*)smem;                              // [16][68] f32 (4352 B)
  float* dws = (float*)(smem + 4352);                     // [6][64] float4 (6144 B)
  float* x3b = (float*)smem;                              // [64][37] f32 (aliases stage)
  unsigned short* xt = (unsigned short*)(smem + 10496);   // [64][512] swizzled (64 KiB)
  float* red = (float*)(smem + 76032);                    // [8]

  int tid = threadIdx.x;
  int t = blockIdx.x, s = blockIdx.y;
  int lb = t*62 - 1;           // global l of x2 col ll=0
  int w = tid >> 6, ln16 = tid & 15, quad = (tid & 63) >> 4;
  int lane8 = (tid & 63)*8;

  const float* hb = h + s*(NSQ*Lc);

  // -------- stage h window + dyn weights (+ bias from L2, pre-barrier) -----
  for (int i = tid; i < 16*68; i += 512) {
    int r = i / 68, col = i - r*68;
    int gl = t*62 - 2 + col;                  // x col ll uses hs[ll..ll+2]
    hs[i] = ((unsigned)gl < 2048u) ? hb[r*Lc + gl] : 0.f;
  }
  for (int i = tid; i < 1536; i += 512) dws[i] = dynW[s*1536 + i];
  int cgx = tid & 63;
  float4 bg0 = *(const float4*)&dynB[s*Cc + cgx*8];
  float4 bg4 = *(const float4*)&dynB[s*Cc + cgx*8 + 4];

  #define LOADAF(ch_, AF_) {                                                  \
    _Pragma("unroll")                                                         \
    for (int mi = 0; mi < 4; mi++)                                            \
      (AF_)[mi] = *(const bf16x8*)&W1p[(((ch_)*32 + w*4 + mi) << 9) + lane8]; \
  }

  bf16x8 afA[4], afB[4];
  LOADAF(0, afA);              // overlap with x-compute below
  __syncthreads();

  // -------- compute x once: thread = (cg 0..63, lg=w 0..7), 8 cols --------
  {
    int cg = cgx;
    int q = cg >> 2;
    float wvv[24];
    const float4* wp4 = (const float4*)dws;
    #pragma unroll
    for (int i = 0; i < 6; i++) {
      float4 v = wp4[i*64 + cg];             // lane-consecutive: conflict-free
      wvv[4*i] = v.x; wvv[4*i+1] = v.y; wvv[4*i+2] = v.z; wvv[4*i+3] = v.w;
    }
    float bxx[8];
    bxx[0]=bg0.x; bxx[1]=bg0.y; bxx[2]=bg0.z; bxx[3]=bg0.w;
    bxx[4]=bg4.x; bxx[5]=bg4.y; bxx[6]=bg4.z; bxx[7]=bg4.w;
    const float* hr = hs + q*68;
    int ll0 = w*8;
    float hm = hr[ll0], hc = hr[ll0+1];
    #pragma unroll
    for (int i = 0; i < 8; i++) {
      int ll = ll0 + i;
      float hp = hr[ll+2];
      float v0 = fmaxf(wvv[0]*hm  + wvv[1]*hc  + wvv[2]*hp  + bxx[0], 0.f);
      float v1 = fmaxf(wvv[3]*hm  + wvv[4]*hc  + wvv[5]*hp  + bxx[1], 0.f);
      float v2 = fmaxf(wvv[6]*hm  + wvv[7]*hc  + wvv[8]*hp  + bxx[2], 0.f);
      float v3 = fmaxf(wvv[9]*hm  + wvv[10]*hc + wvv[11]*hp + bxx[3], 0.f);
      float v4 = fmaxf(wvv[12]*hm + wvv[13]*hc + wvv[14]*hp + bxx[4], 0.f);
      float v5 = fmaxf(wvv[15]*hm + wvv[16]*hc + wvv[17]*hp + bxx[5], 0.f);
      float v6 = fmaxf(wvv[18]*hm + wvv[19]*hc + wvv[20]*hp + bxx[6], 0.f);
      float v7 = fmaxf(wvv[21]*hm + wvv[22]*hc + wvv[23]*hp + bxx[7], 0.f);
      uint4 st;
      st.x = cvt_pk_bf16(v0, v1);
      st.y = cvt_pk_bf16(v2, v3);
      st.z = cvt_pk_bf16(v4, v5);
      st.w = cvt_pk_bf16(v6, v7);
      *(uint4*)&xt[xoff(ll, cg)] = st;     // 16B aligned (xoff multiple of 8 shorts)
      hm = hc; hc = hp;
    }
  }

  floatx4 acc[4][4];
  #pragma unroll
  for (int mi = 0; mi < 4; mi++)
    #pragma unroll
    for (int ni = 0; ni < 4; ni++)
      acc[mi][ni] = (floatx4){0.f,0.f,0.f,0.f};

  // Precomputed swizzle bases for phase A B-fragment reads:
  // xoff(ni*16+ln16, ch*4+quad) = X + 32*e4 + ch*32 (ch even)
  //                             = X - 32*e4 + ch*32 (ch odd)
  int e4 = (ln16 >> 2) & 1;
  int bE[4], bO[4];
  #pragma unroll
  for (int ni = 0; ni < 4; ni++) {
    int row = ni*16 + ln16;
    int X = row*512 + ((quad ^ (ln16 & 3)) << 3);
    bE[ni] = X + 32*e4;
    bO[ni] = X - 32*e4;
  }

  #define CHUNK(ch_, AFC_, AFN_, PF_) {                                       \
    if (PF_) LOADAF((ch_) + 1, AFN_);                                         \
    bf16x8 bfr[4];                                                            \
    _Pragma("unroll")                                                         \
    for (int ni = 0; ni < 4; ni++)                                            \
      bfr[ni] = *(const bf16x8*)&xt[(((ch_) & 1) ? bO[ni] : bE[ni]) + (ch_)*32]; \
    __builtin_amdgcn_s_setprio(1);                                            \
    _Pragma("unroll")                                                         \
    for (int ni = 0; ni < 4; ni++)                                            \
      _Pragma("unroll")                                                       \
      for (int mi = 0; mi < 4; mi++)                                          \
        acc[mi][ni] = __builtin_amdgcn_mfma_f32_16x16x32_bf16((AFC_)[mi], bfr[ni], acc[mi][ni], 0, 0, 0); \
    __builtin_amdgcn_s_setprio(0);                                            \
  }

  __syncthreads();   // x ready

  // -------- phase A: 16 K-chunks, barrier-free, af double-buffered --------
  #pragma unroll 1
  for (int cp = 0; cp < 8; cp++) {
    CHUNK(2*cp,     afA, afB, 1);
    CHUNK(2*cp + 1, afB, afA, (cp < 7));
  }
  __syncthreads();   // all x reads done before x2 overwrites the region

  // -------- epilogue A: relu+b1 -> x2 in xt (bf16), zero invalid l --------
  #pragma unroll
  for (int mi = 0; mi < 4; mi++) {
    int o = w*64 + mi*16 + quad*4;
    float4 b1v = *(const float4*)(b1 + o);
    int cg = o >> 3, half = (quad & 1)*4;
    #pragma unroll
    for (int ni = 0; ni < 4; ni++) {
      int ll = ni*16 + ln16;
      int gl = lb + ll;
      uint2 st;
      if ((unsigned)gl < 2048u) {
        st.x = cvt_pk_bf16(fmaxf(acc[mi][ni][0] + b1v.x, 0.f),
                           fmaxf(acc[mi][ni][1] + b1v.y, 0.f));
        st.y = cvt_pk_bf16(fmaxf(acc[mi][ni][2] + b1v.z, 0.f),
                           fmaxf(acc[mi][ni][3] + b1v.w, 0.f));
      } else {
        st.x = 0u; st.y = 0u;              // conv2 zero-pad columns
      }
      *(uint2*)&xt[xoff(ll, cg) + half] = st;
    }
  }
  __syncthreads();

  // -------- phase B: waves 0-3 conv (both jh); waves 4-7 h1 copy --------
  if (w < 4) {
    __builtin_amdgcn_s_setprio(1);
    floatx4 ca0 = (floatx4){0.f,0.f,0.f,0.f};
    floatx4 ca1 = (floatx4){0.f,0.f,0.f,0.f};
    int ll = w*16 + ln16;
    #pragma unroll
    for (int k = 0; k < 3; k++) {
      int rr = ll - 1 + k;
      rr = (rr < 0) ? 0 : ((rr > 63) ? 63 : rr);   // edges discarded
      // xoff(rr, cc*4+quad) = Xk +- 32*er + cc*32 (sign by cc parity)
      int er = (rr >> 2) & 1;
      int Xk = rr*512 + ((quad ^ (rr & 3)) << 3);
      int bEk = Xk + 32*er, bOk = Xk - 32*er;
      #pragma unroll
      for (int cc = 0; cc < 16; cc++) {
        bf16x8 v0 = *(const bf16x8*)&xt[((cc & 1) ? bOk : bEk) + cc*32];
        bf16x8 a0 = *(const bf16x8*)&W2p[(((k*2 + 0)*16 + cc) << 9) + lane8];
        ca0 = __builtin_amdgcn_mfma_f32_16x16x32_bf16(a0, v0, ca0, 0, 0, 0);
        bf16x8 a1 = *(const bf16x8*)&W2p[(((k*2 + 1)*16 + cc) << 9) + lane8];
        ca1 = __builtin_amdgcn_mfma_f32_16x16x32_bf16(a1, v0, ca1, 0, 0, 0);
      }
    }
    __builtin_amdgcn_s_setprio(0);
    float4 b2v0 = *(const float4*)(b2 + quad*4);
    float4 b2v1 = *(const float4*)(b2 + 16 + quad*4);
    float4 st0, st1;
    st0.x = ca0[0] + b2v0.x; st0.y = ca0[1] + b2v0.y;
    st0.z = ca0[2] + b2v0.z; st0.w = ca0[3] + b2v0.w;
    st1.x = ca1[0] + b2v1.x; st1.y = ca1[1] + b2v1.y;
    st1.z = ca1[2] + b2v1.z; st1.w = ca1[3] + b2v1.w;
    *(float4*)&x3b[ll*37 + quad*4] = st0;
    *(float4*)&x3b[ll*37 + 16 + quad*4] = st1;
  } else {
    // h1 passthrough: rows q 0..15, cols l = lb+1 .. lb+62
    int lane = tid & 63;
    int base = (w - 4)*64 + lane;          // 0..255
    #pragma unroll
    for (int i = 0; i < 4; i++) {
      int idx = base + i*256;              // 0..1023 = (q 0..15) x (ll 0..63)
      int ll = idx & 63, q = idx >> 6;
      int l = lb + ll;
      if (ll >= 1 && ll <= 62 && l < 2048) {
        int gi = s*(NSQ*Lc) + q*Lc + l;
        out[gi] = h[gi];
      }
    }
  }

  // prefetch phase-C h2 values: loads in flight across the barrier wait
  float hpre[2]; int gidx2[2]; bool val2[2];
  #pragma unroll
  for (int i = 0; i < 2; i++) {
    int idx = tid + i*512;           // 0..1023 = (q16 0..15) x (ll 0..63)
    int ll = idx & 63, q = 16 + (idx >> 6);
    int l = lb + ll;
    val2[i] = (ll >= 1 && ll <= 62 && l < 2048);
    gidx2[i] = s*(NSQ*Lc) + q*Lc + l;
    hpre[i] = val2[i] ? h[gidx2[i]] : 0.f;
  }
  __syncthreads();

  // -------- phase C: h2 rows only: sigmoid/affine/out + logdet --------
  float ld = 0.f;
  #pragma unroll
  for (int i = 0; i < 2; i++) {
    int idx = tid + i*512;
    int ll = idx & 63, q16 = idx >> 6;
    if (val2[i]) {
      float sv = 1.f / (1.f + __expf(-(x3b[ll*37 + q16] + 2.f))) + 1e-7f;
      float mv = x3b[ll*37 + q16 + 16];
      out[gidx2[i]] = sv * (hpre[i] + mv);
      ld += __logf(sv);
    }
  }
  #pragma unroll
  for (int off = 32; off > 0; off >>= 1) ld += __shfl_down(ld, off);
  if ((tid & 63) == 0) red[w] = ld;
  __syncthreads();
  if (tid == 0) {
    float tot = 0.f;
    #pragma unroll
    for (int i = 0; i < 8; i++) tot += red[i];
    atomicAdd(&out[OUT_H + s], tot);
  }
}

// ---------------------------------------------------------------------------
extern "C" void kernel_launch(void* const* d_in, const int* in_sizes, int n_in,
                              void* d_out, int out_size, void* d_ws, size_t ws_size,
                              hipStream_t stream) {
  const float* h   = (const float*)d_in[0];
  const float* emb = (const float*)d_in[1];
  const float* Wa  = (const float*)d_in[2];
  const float* ba  = (const float*)d_in[3];
  const float* Wb  = (const float*)d_in[4];
  const float* bb  = (const float*)d_in[5];
  const float* W1  = (const float*)d_in[6];
  const float* b1  = (const float*)d_in[7];
  const float* W2  = (const float*)d_in[8];
  const float* b2  = (const float*)d_in[9];
  float* out = (float*)d_out;
  char* ws = (char*)d_ws;

  float* dynW = (float*)(ws + 0);                          // 384 KiB (transposed)
  float* dynB = (float*)(ws + 393216);                     // 128 KiB
  unsigned short* W1p = (unsigned short*)(ws + 524288);    // 512 KiB (packed)
  unsigned short* W2p = (unsigned short*)(ws + 1048576);   // 96 KiB (packed)
  if (ws_size < 1179648ull) return;                        // ~1.2 MB needed

  const int smem_bytes = 76064;  // stage/x3b 10496 + xt 65536 + red 32
  (void)hipFuncSetAttribute((const void*)k_fused11,
                            hipFuncAttributeMaxDynamicSharedMemorySize,
                            smem_bytes);

  k_prep<<<512, 256, 0, stream>>>(emb, Wa, ba, Wb, bb, W1, W2,
                                  dynW, dynB, W1p, W2p, out);
  k_fused11<<<dim3(34, 64), 512, smem_bytes, stream>>>(h, W1p, b1, W2p, b2,
                                                       dynW, dynB, out);
}

// Round 3
// 193.789 us; speedup vs baseline: 1.0485x; 1.0485x over previous
//
#include <hip/hip_runtime.h>
#include <stdint.h>

#define S 64
#define NSQ 32
#define Lc 2048
#define Cc 512
#define Ec 128
#define OUT_H (S*NSQ*Lc)   /* 4194304 */

typedef __bf16 bf16x8 __attribute__((ext_vector_type(8)));
typedef float floatx4 __attribute__((ext_vector_type(4)));

__device__ __forceinline__ unsigned short f2bf(float f){
  union { float f; uint32_t u; } v; v.f = f;
  uint32_t r = v.u + 0x7fffu + ((v.u >> 16) & 1u);
  return (unsigned short)(r >> 16);
}

// packed f32x2 -> bf16x2 (RNE), 1 instruction on gfx950
__device__ __forceinline__ uint32_t cvt_pk_bf16(float lo, float hi){
  uint32_t r;
  asm("v_cvt_pk_bf16_f32 %0, %1, %2" : "=v"(r) : "v"(lo), "v"(hi));
  return r;
}

// XOR-swizzled LDS offset (shorts) for the x/x2 tile (row stride 512).
__device__ __forceinline__ int xoff(int row, int cg) {
  return row*512 + (((cg) ^ (row & 7)) << 3);
}

// ---------------------------------------------------------------------------
// k_prep: adapt dots (coalesced + shfl reduce); W1/W2 -> MFMA-fragment-packed
// bf16; zero logdet.   grid 1024 x 256 (adapt split 2x finer for TLP; packs
// run on blocks < 512 only).
// dynW transposed: thread cg reads float4 j4 at dynW[s*1536 + j4*256 + cg*4+..]
// W1p: frag = ch*32 + o16; elem(lane,j) = W1[o16*16+(lane&15)][ch*32+(lane>>4)*8+j]
// W2p: frag = (k*2+jh)*16 + cc; elem(lane,j) = W2[jh*16+(lane&15)][cc*32+(lane>>4)*8+j][k]
// ---------------------------------------------------------------------------
__global__ void k_prep(const float* __restrict__ emb,
                       const float* __restrict__ Wa, const float* __restrict__ ba,
                       const float* __restrict__ Wb, const float* __restrict__ bb,
                       const float* __restrict__ W1, const float* __restrict__ W2,
                       float* __restrict__ dynW, float* __restrict__ dynB,
                       unsigned short* __restrict__ W1p, unsigned short* __restrict__ W2p,
                       float* __restrict__ out)
{
  __shared__ float embl[Ec];
  int tid = threadIdx.x;
  int b = blockIdx.x;          // 1024 blocks, 16 per sample for adapt
  int s = b >> 4, g = b & 15;
  if (tid < Ec) embl[tid] = emb[s*Ec + tid];
  __syncthreads();
  {
    int w = tid >> 6, lane = tid & 63, le = lane & 31, rh = lane >> 5;
    float4 ev = *(const float4*)&embl[le*4];
    int base_o = g*128 + w*32;
    #pragma unroll 4
    for (int p = 0; p < 16; p++) {
      int ro = base_o + p*2 + rh;
      bool isA = ro < 1536;
      const float* rp = isA ? (Wa + ro*Ec) : (Wb + (ro - 1536)*Ec);
      float4 wv = *(const float4*)&rp[le*4];
      float part = wv.x*ev.x + wv.y*ev.y + wv.z*ev.z + wv.w*ev.w;
      part += __shfl_xor(part, 1, 32);
      part += __shfl_xor(part, 2, 32);
      part += __shfl_xor(part, 4, 32);
      part += __shfl_xor(part, 8, 32);
      part += __shfl_xor(part, 16, 32);
      if (le == 0) {
        if (isA) {
          // transposed write (see header comment)
          int ch = ro / 3, k = ro - ch*3;
          int cgc = ch >> 3, j = (ch & 7)*3 + k;
          dynW[s*1536 + (j >> 2)*256 + cgc*4 + (j & 3)] = part + ba[ro];
        } else {
          dynB[s*Cc + (ro - 1536)] = part + bb[ro - 1536];
        }
      }
    }
  }

  if (b < 512) {
    int gtid = b*256 + tid;      // 0..131071
    // W1 pack: 262144 elems, 2 per thread (j pairs)
    {
      int d0 = gtid*2;
      int j0 = d0 & 7;
      int lane = (d0 >> 3) & 63;
      int frag = d0 >> 9;
      int o16 = frag & 31, ch = frag >> 5;
      int oo = o16*16 + (lane & 15);
      int cc = ch*32 + (lane >> 4)*8 + j0;
      float2 wv = *(const float2*)&W1[oo*512 + cc];
      ((uint32_t*)W1p)[gtid] = cvt_pk_bf16(wv.x, wv.y);
    }
    // W2 pack: 49152 elems; coalesced source reads, scattered 2B dest writes
    if (gtid < 49152) {
      int e = gtid;
      int jj = e / 1536;
      int r = e - jj*1536;
      int c = r / 3, k = r - c*3;
      int cc = c >> 5, hi = (c >> 3) & 3, j = c & 7;
      int jh = jj >> 4, lo = jj & 15;
      int lane = hi*16 + lo;
      int frag = (k*2 + jh)*16 + cc;
      W2p[(frag << 9) + lane*8 + j] = f2bf(W2[e]);
    }
    if (gtid < S) out[OUT_H + gtid] = 0.f;   // logdet accumulators
  }
}

// ---------------------------------------------------------------------------
// k_fused12: vs k_fused11 —
//  - phase B rebalanced: ALL 8 waves conv (wave = (ll-quarter, jh), 48 MFMA
//    each) — halves the conv wall; no waves idling at the barrier
//  - h1 passthrough moved into epilogue A (short-lived regs, overlaps LDS
//    writes + phase-B a-load warmup)
//  - phase-A CHUNK issues bfr ds_reads BEFORE the af global loads (LDS
//    latency hides under vmem issue)
// x2 col ll <-> global l = t*62 - 1 + ll; valid outputs ll in [1,62].
// ---------------------------------------------------------------------------
__global__ void __launch_bounds__(512, 4) k_fused12(
    const float* __restrict__ h,
    const unsigned short* __restrict__ W1p, const float* __restrict__ b1,
    const unsigned short* __restrict__ W2p, const float* __restrict__ b2,
    const float* __restrict__ dynW, const float* __restrict__ dynB,
    float* __restrict__ out)
{
  extern __shared__ char smem[];
  float* hs  = (float*)smem;                              // [16][68] f32 (4352 B)
  float* dws = (float*)(smem + 4352);                     // [6][64] float4 (6144 B)
  float* x3b = (float*)smem;                              // [64][37] f32 (aliases stage)
  unsigned short* xt = (unsigned short*)(smem + 10496);   // [64][512] swizzled (64 KiB)
  float* red = (float*)(smem + 76032);                    // [8]

  int tid = threadIdx.x;
  int t = blockIdx.x, s = blockIdx.y;
  int lb = t*62 - 1;           // global l of x2 col ll=0
  int w = tid >> 6, ln16 = tid & 15, quad = (tid & 63) >> 4;
  int lane8 = (tid & 63)*8;

  const float* hb = h + s*(NSQ*Lc);

  // -------- stage h window + dyn weights (+ bias from L2, pre-barrier) -----
  for (int i = tid; i < 16*68; i += 512) {
    int r = i / 68, col = i - r*68;
    int gl = t*62 - 2 + col;                  // x col ll uses hs[ll..ll+2]
    hs[i] = ((unsigned)gl < 2048u) ? hb[r*Lc + gl] : 0.f;
  }
  for (int i = tid; i < 1536; i += 512) dws[i] = dynW[s*1536 + i];
  int cgx = tid & 63;
  float4 bg0 = *(const float4*)&dynB[s*Cc + cgx*8];
  float4 bg4 = *(const float4*)&dynB[s*Cc + cgx*8 + 4];

  #define LOADAF(ch_, AF_) {                                                  \
    _Pragma("unroll")                                                         \
    for (int mi = 0; mi < 4; mi++)                                            \
      (AF_)[mi] = *(const bf16x8*)&W1p[(((ch_)*32 + w*4 + mi) << 9) + lane8]; \
  }

  bf16x8 afA[4], afB[4];
  LOADAF(0, afA);              // overlap with x-compute below
  __syncthreads();

  // -------- compute x once: thread = (cg 0..63, lg=w 0..7), 8 cols --------
  {
    int cg = cgx;
    int q = cg >> 2;
    float wvv[24];
    const float4* wp4 = (const float4*)dws;
    #pragma unroll
    for (int i = 0; i < 6; i++) {
      float4 v = wp4[i*64 + cg];             // lane-consecutive: conflict-free
      wvv[4*i] = v.x; wvv[4*i+1] = v.y; wvv[4*i+2] = v.z; wvv[4*i+3] = v.w;
    }
    float bxx[8];
    bxx[0]=bg0.x; bxx[1]=bg0.y; bxx[2]=bg0.z; bxx[3]=bg0.w;
    bxx[4]=bg4.x; bxx[5]=bg4.y; bxx[6]=bg4.z; bxx[7]=bg4.w;
    const float* hr = hs + q*68;
    int ll0 = w*8;
    float hm = hr[ll0], hc = hr[ll0+1];
    #pragma unroll
    for (int i = 0; i < 8; i++) {
      int ll = ll0 + i;
      float hp = hr[ll+2];
      float v0 = fmaxf(wvv[0]*hm  + wvv[1]*hc  + wvv[2]*hp  + bxx[0], 0.f);
      float v1 = fmaxf(wvv[3]*hm  + wvv[4]*hc  + wvv[5]*hp  + bxx[1], 0.f);
      float v2 = fmaxf(wvv[6]*hm  + wvv[7]*hc  + wvv[8]*hp  + bxx[2], 0.f);
      float v3 = fmaxf(wvv[9]*hm  + wvv[10]*hc + wvv[11]*hp + bxx[3], 0.f);
      float v4 = fmaxf(wvv[12]*hm + wvv[13]*hc + wvv[14]*hp + bxx[4], 0.f);
      float v5 = fmaxf(wvv[15]*hm + wvv[16]*hc + wvv[17]*hp + bxx[5], 0.f);
      float v6 = fmaxf(wvv[18]*hm + wvv[19]*hc + wvv[20]*hp + bxx[6], 0.f);
      float v7 = fmaxf(wvv[21]*hm + wvv[22]*hc + wvv[23]*hp + bxx[7], 0.f);
      uint4 st;
      st.x = cvt_pk_bf16(v0, v1);
      st.y = cvt_pk_bf16(v2, v3);
      st.z = cvt_pk_bf16(v4, v5);
      st.w = cvt_pk_bf16(v6, v7);
      *(uint4*)&xt[xoff(ll, cg)] = st;     // 16B aligned (xoff multiple of 8 shorts)
      hm = hc; hc = hp;
    }
  }

  floatx4 acc[4][4];
  #pragma unroll
  for (int mi = 0; mi < 4; mi++)
    #pragma unroll
    for (int ni = 0; ni < 4; ni++)
      acc[mi][ni] = (floatx4){0.f,0.f,0.f,0.f};

  // Precomputed swizzle bases for phase A B-fragment reads:
  // xoff(ni*16+ln16, ch*4+quad) = X + 32*e4 + ch*32 (ch even)
  //                             = X - 32*e4 + ch*32 (ch odd)
  int e4 = (ln16 >> 2) & 1;
  int bE[4], bO[4];
  #pragma unroll
  for (int ni = 0; ni < 4; ni++) {
    int row = ni*16 + ln16;
    int X = row*512 + ((quad ^ (ln16 & 3)) << 3);
    bE[ni] = X + 32*e4;
    bO[ni] = X - 32*e4;
  }

  #define CHUNK(ch_, AFC_, AFN_, PF_) {                                       \
    bf16x8 bfr[4];                                                            \
    _Pragma("unroll")                                                         \
    for (int ni = 0; ni < 4; ni++)                                            \
      bfr[ni] = *(const bf16x8*)&xt[(((ch_) & 1) ? bO[ni] : bE[ni]) + (ch_)*32]; \
    if (PF_) LOADAF((ch_) + 1, AFN_);                                         \
    __builtin_amdgcn_s_setprio(1);                                            \
    _Pragma("unroll")                                                         \
    for (int ni = 0; ni < 4; ni++)                                            \
      _Pragma("unroll")                                                       \
      for (int mi = 0; mi < 4; mi++)                                          \
        acc[mi][ni] = __builtin_amdgcn_mfma_f32_16x16x32_bf16((AFC_)[mi], bfr[ni], acc[mi][ni], 0, 0, 0); \
    __builtin_amdgcn_s_setprio(0);                                            \
  }

  __syncthreads();   // x ready

  // -------- phase A: 16 K-chunks, barrier-free, af double-buffered --------
  #pragma unroll 1
  for (int cp = 0; cp < 8; cp++) {
    CHUNK(2*cp,     afA, afB, 1);
    CHUNK(2*cp + 1, afB, afA, (cp < 7));
  }
  __syncthreads();   // all x reads done before x2 overwrites the region

  // -------- epilogue A: relu+b1 -> x2 in xt (bf16), zero invalid l;
  //          plus h1 passthrough (independent global traffic, overlaps) -----
  #pragma unroll
  for (int mi = 0; mi < 4; mi++) {
    int o = w*64 + mi*16 + quad*4;
    float4 b1v = *(const float4*)(b1 + o);
    int cg = o >> 3, half = (quad & 1)*4;
    #pragma unroll
    for (int ni = 0; ni < 4; ni++) {
      int ll = ni*16 + ln16;
      int gl = lb + ll;
      uint2 st;
      if ((unsigned)gl < 2048u) {
        st.x = cvt_pk_bf16(fmaxf(acc[mi][ni][0] + b1v.x, 0.f),
                           fmaxf(acc[mi][ni][1] + b1v.y, 0.f));
        st.y = cvt_pk_bf16(fmaxf(acc[mi][ni][2] + b1v.z, 0.f),
                           fmaxf(acc[mi][ni][3] + b1v.w, 0.f));
      } else {
        st.x = 0u; st.y = 0u;              // conv2 zero-pad columns
      }
      *(uint2*)&xt[xoff(ll, cg) + half] = st;
    }
  }
  // h1 passthrough: rows q 0..15, cols l = lb+1 .. lb+62 (all 8 waves)
  #pragma unroll
  for (int i = 0; i < 2; i++) {
    int idx = tid + i*512;               // 0..1023 = (q 0..15) x (ll 0..63)
    int ll = idx & 63, q = idx >> 6;
    int l = lb + ll;
    if (ll >= 1 && ll <= 62 && l < 2048) {
      int gi = s*(NSQ*Lc) + q*Lc + l;
      out[gi] = h[gi];
    }
  }
  __syncthreads();

  // -------- phase B: all 8 waves conv; wave = (lq = w>>1, jh = w&1) --------
  {
    int lq = w >> 1, jh = w & 1;
    int ll = lq*16 + ln16;
    floatx4 ca = (floatx4){0.f,0.f,0.f,0.f};
    __builtin_amdgcn_s_setprio(1);
    #pragma unroll
    for (int k = 0; k < 3; k++) {
      int rr = ll - 1 + k;
      rr = (rr < 0) ? 0 : ((rr > 63) ? 63 : rr);   // edges discarded
      // xoff(rr, cc*4+quad) = Xk +- 32*er + cc*32 (sign by cc parity)
      int er = (rr >> 2) & 1;
      int Xk = rr*512 + ((quad ^ (rr & 3)) << 3);
      int bEk = Xk + 32*er, bOk = Xk - 32*er;
      #pragma unroll
      for (int cc = 0; cc < 16; cc++) {
        bf16x8 v0 = *(const bf16x8*)&xt[((cc & 1) ? bOk : bEk) + cc*32];
        bf16x8 a0 = *(const bf16x8*)&W2p[(((k*2 + jh)*16 + cc) << 9) + lane8];
        ca = __builtin_amdgcn_mfma_f32_16x16x32_bf16(a0, v0, ca, 0, 0, 0);
      }
    }
    __builtin_amdgcn_s_setprio(0);
    float4 b2v = *(const float4*)(b2 + jh*16 + quad*4);
    float4 st;
    st.x = ca[0] + b2v.x; st.y = ca[1] + b2v.y;
    st.z = ca[2] + b2v.z; st.w = ca[3] + b2v.w;
    *(float4*)&x3b[ll*37 + jh*16 + quad*4] = st;
  }

  // prefetch phase-C h2 values: loads in flight across the barrier wait
  float hpre[2]; int gidx2[2]; bool val2[2];
  #pragma unroll
  for (int i = 0; i < 2; i++) {
    int idx = tid + i*512;           // 0..1023 = (q16 0..15) x (ll 0..63)
    int ll = idx & 63, q = 16 + (idx >> 6);
    int l = lb + ll;
    val2[i] = (ll >= 1 && ll <= 62 && l < 2048);
    gidx2[i] = s*(NSQ*Lc) + q*Lc + l;
    hpre[i] = val2[i] ? h[gidx2[i]] : 0.f;
  }
  __syncthreads();

  // -------- phase C: h2 rows only: sigmoid/affine/out + logdet --------
  float ld = 0.f;
  #pragma unroll
  for (int i = 0; i < 2; i++) {
    int idx = tid + i*512;
    int ll = idx & 63, q16 = idx >> 6;
    if (val2[i]) {
      float sv = 1.f / (1.f + __expf(-(x3b[ll*37 + q16] + 2.f))) + 1e-7f;
      float mv = x3b[ll*37 + q16 + 16];
      out[gidx2[i]] = sv * (hpre[i] + mv);
      ld += __logf(sv);
    }
  }
  #pragma unroll
  for (int off = 32; off > 0; off >>= 1) ld += __shfl_down(ld, off);
  if ((tid & 63) == 0) red[w] = ld;
  __syncthreads();
  if (tid == 0) {
    float tot = 0.f;
    #pragma unroll
    for (int i = 0; i < 8; i++) tot += red[i];
    atomicAdd(&out[OUT_H + s], tot);
  }
}

// ---------------------------------------------------------------------------
extern "C" void kernel_launch(void* const* d_in, const int* in_sizes, int n_in,
                              void* d_out, int out_size, void* d_ws, size_t ws_size,
                              hipStream_t stream) {
  const float* h   = (const float*)d_in[0];
  const float* emb = (const float*)d_in[1];
  const float* Wa  = (const float*)d_in[2];
  const float* ba  = (const float*)d_in[3];
  const float* Wb  = (const float*)d_in[4];
  const float* bb  = (const float*)d_in[5];
  const float* W1  = (const float*)d_in[6];
  const float* b1  = (const float*)d_in[7];
  const float* W2  = (const float*)d_in[8];
  const float* b2  = (const float*)d_in[9];
  float* out = (float*)d_out;
  char* ws = (char*)d_ws;

  float* dynW = (float*)(ws + 0);                          // 384 KiB (transposed)
  float* dynB = (float*)(ws + 393216);                     // 128 KiB
  unsigned short* W1p = (unsigned short*)(ws + 524288);    // 512 KiB (packed)
  unsigned short* W2p = (unsigned short*)(ws + 1048576);   // 96 KiB (packed)
  if (ws_size < 1179648ull) return;                        // ~1.2 MB needed

  const int smem_bytes = 76064;  // stage/x3b 10496 + xt 65536 + red 32
  (void)hipFuncSetAttribute((const void*)k_fused12,
                            hipFuncAttributeMaxDynamicSharedMemorySize,
                            smem_bytes);

  k_prep<<<1024, 256, 0, stream>>>(emb, Wa, ba, Wb, bb, W1, W2,
                                   dynW, dynB, W1p, W2p, out);
  k_fused12<<<dim3(34, 64), 512, smem_bytes, stream>>>(h, W1p, b1, W2p, b2,
                                                       dynW, dynB, out);
}